// Round 3
// baseline (4277.542 us; speedup 1.0000x reference)
//
#include <hip/hip_runtime.h>

#define Tn 1024
#define Bn 64
#define In_ 64
#define Hn 512
#define On 64
#define NG 8     // batch groups (8 batches each)
#define MB 8     // batches per group
#define NJ 16    // j-slice blocks per group
#define NS 32    // j columns per block
#define DTC 0.5f

typedef __attribute__((ext_vector_type(8))) short short8;   // bf16x8 MFMA frag
typedef __attribute__((ext_vector_type(4))) float floatx4;  // MFMA C frag
typedef unsigned long long u64;

__device__ __forceinline__ float bf2f(unsigned short u){
  union{unsigned int i; float f;} v; v.i = ((unsigned int)u)<<16; return v.f;
}
__device__ __forceinline__ unsigned short f2bf(float f){   // RNE
  union{float f; unsigned int i;} v; v.f=f;
  unsigned int x=v.i;
  return (unsigned short)((x + 0x7fffu + ((x>>16)&1u))>>16);
}
__device__ __forceinline__ void split8(const float* p, short8& hi, short8& lo){
  #pragma unroll
  for (int e = 0; e < 8; e++){
    float x = p[e];
    unsigned short h = f2bf(x);
    hi[e] = (short)h;
    lo[e] = (short)f2bf(x - bf2f(h));
  }
}

// Persistent scan: 128 blocks = 8 batch-groups x 16 j-slices. wrec (hi+lo bf16)
// register-resident all 1024 steps. Cross-block h exchange via self-validating
// 8B packets {tag, hi, lo} with relaxed agent-scope atomics (device coherence
// point) -- NO fences, NO flag round-trip. Parity double-buffer prevents
// overwrite-before-read (max skew 2 publishes; parity separation guarantees
// the consumer read happened before reuse).
__global__ __launch_bounds__(256,1) void rnn_scan(
    const float* __restrict__ inp,   // [B,T,I] fp32
    const float* __restrict__ wi,    // [I,H]
    const float* __restrict__ wrec,  // [H,H]
    const float* __restrict__ brec,  // [H]
    const float* __restrict__ h0,    // [H]
    unsigned short* __restrict__ hs, // ws [B,T,H] bf16
    u64* __restrict__ Hpkt)          // ws [2][NG][MB][Hn] packets
{
  const int tid  = threadIdx.x;
  const int bid  = blockIdx.x;
  const int g    = bid & (NG-1);
  const int jb   = bid >> 3;
  const int wv   = tid >> 6;
  const int lane = tid & 63;
  const int col  = lane & 15;
  const int quad = lane >> 4;

  __shared__ __align__(16) unsigned short hAhi[16][520];
  __shared__ __align__(16) unsigned short hAlo[16][520];
  __shared__ __align__(16) float red[16][32][4];

  // zero LDS once: rows 8..15 stay zero (M=16 pad); rows 0..7 rewritten per step
  for (int idx = tid; idx < 16*520; idx += 256){
    int r = idx/520, c = idx - r*520;
    hAhi[r][c] = 0; hAlo[r][c] = 0;
  }

  // wrec B-frags (hi+lo): B[k][j]=wrec[j][k], j=jb*32+nt*16+col, k=wv*128+kk*32+quad*8
  short8 bwh[4][2], bwl[4][2];
  #pragma unroll
  for (int kk = 0; kk < 4; kk++)
    #pragma unroll
    for (int nt = 0; nt < 2; nt++){
      int j = jb*NS + nt*16 + col;
      int k = wv*128 + kk*32 + quad*8;
      split8(wrec + (size_t)j*Hn + k, bwh[kk][nt], bwl[kk][nt]);
    }
  // wave0: wi B-frags (hi+lo), per-lane gather once
  short8 wih[2][2], wil[2][2];
  if (wv == 0){
    #pragma unroll
    for (int kk = 0; kk < 2; kk++)
      #pragma unroll
      for (int nt = 0; nt < 2; nt++){
        int j = jb*NS + nt*16 + col;
        float tmp[8];
        #pragma unroll
        for (int e = 0; e < 8; e++) tmp[e] = wi[(size_t)(kk*32 + quad*8 + e)*Hn + j];
        split8(tmp, wih[kk][nt], wil[kk][nt]);
      }
  }
  const int eb = tid >> 5;              // epilogue batch-in-group (0..7)
  const int ej = tid & 31;              // epilogue j-in-slice
  const float brec_e = brec[jb*NS + ej];
  const int bglob = g*MB + eb;
  const int inrow = g*MB + (col & 7);
  const int pr = tid >> 5;              // consumer packet row (== eb)
  const int pc = (tid & 31) * 16;       // consumer packet col base (16 j/thread)

  // prologue: jb==0 block publishes h0 as tag-0 packets into parity-0 buffer
  if (jb == 0){
    #pragma unroll
    for (int i = 0; i < 16; i++){
      int c = pc + i;
      float x = h0[c];
      unsigned short h_ = f2bf(x);
      unsigned short l_ = f2bf(x - bf2f(h_));
      u64 pkt = (((u64)0u) << 32) | ((unsigned)h_ << 16) | (unsigned)l_;
      __hip_atomic_store(&Hpkt[(((size_t)0*NG + g)*MB + pr)*Hn + c], pkt,
                         __ATOMIC_RELAXED, __HIP_MEMORY_SCOPE_AGENT);
    }
  }
  __syncthreads();

  for (int t = 0; t < Tn; t++){
    // issue input loads early (independent of packet arrival)
    short8 aih[2], ail[2];
    if (wv == 0){
      #pragma unroll
      for (int kk = 0; kk < 2; kk++)
        split8(inp + ((size_t)inrow*Tn + t)*In_ + kk*32 + quad*8, aih[kk], ail[kk]);
    }

    // poll h_t packets (tag == t) from parity buffer t&1; 16 per thread
    {
      const u64* src = Hpkt + (((size_t)(t&1)*NG + g)*MB + pr)*Hn + pc;
      u64 pkt[16];
      #pragma unroll
      for (int i = 0; i < 16; i++)
        pkt[i] = __hip_atomic_load(src + i, __ATOMIC_RELAXED, __HIP_MEMORY_SCOPE_AGENT);
      const unsigned want = (unsigned)t;
      while (true){
        bool all = true;
        #pragma unroll
        for (int i = 0; i < 16; i++){
          if ((unsigned)(pkt[i] >> 32) != want){
            all = false;
            pkt[i] = __hip_atomic_load(src + i, __ATOMIC_RELAXED, __HIP_MEMORY_SCOPE_AGENT);
          }
        }
        if (all) break;
        __builtin_amdgcn_s_sleep(1);
      }
      // unpack {hi,lo} into LDS (two short8 per plane)
      short8 vh0, vh1, vl0, vl1;
      #pragma unroll
      for (int e = 0; e < 8; e++){
        unsigned w0 = (unsigned)pkt[e];
        unsigned w1 = (unsigned)pkt[8 + e];
        vh0[e] = (short)(w0 >> 16); vl0[e] = (short)(w0 & 0xffffu);
        vh1[e] = (short)(w1 >> 16); vl1[e] = (short)(w1 & 0xffffu);
      }
      *(short8*)&hAhi[pr][pc]     = vh0;
      *(short8*)&hAhi[pr][pc + 8] = vh1;
      *(short8*)&hAlo[pr][pc]     = vl0;
      *(short8*)&hAlo[pr][pc + 8] = vl1;
    }
    __syncthreads();

    // pre[b,j] partial over this wave's K-quarter; hi/lo cross terms (drop lo*lo)
    floatx4 acc[2] = {{0.f,0.f,0.f,0.f},{0.f,0.f,0.f,0.f}};
    #pragma unroll
    for (int kk = 0; kk < 4; kk++){
      int k = wv*128 + kk*32 + quad*8;
      short8 ahi = *(const short8*)&hAhi[col][k];
      short8 alo = *(const short8*)&hAlo[col][k];
      #pragma unroll
      for (int nt = 0; nt < 2; nt++){
        acc[nt] = __builtin_amdgcn_mfma_f32_16x16x32_bf16(ahi, bwh[kk][nt], acc[nt], 0,0,0);
        acc[nt] = __builtin_amdgcn_mfma_f32_16x16x32_bf16(ahi, bwl[kk][nt], acc[nt], 0,0,0);
        acc[nt] = __builtin_amdgcn_mfma_f32_16x16x32_bf16(alo, bwh[kk][nt], acc[nt], 0,0,0);
      }
    }
    if (wv == 0){  // fold xproj = input@wi
      #pragma unroll
      for (int kk = 0; kk < 2; kk++)
        #pragma unroll
        for (int nt = 0; nt < 2; nt++){
          acc[nt] = __builtin_amdgcn_mfma_f32_16x16x32_bf16(aih[kk], wih[kk][nt], acc[nt], 0,0,0);
          acc[nt] = __builtin_amdgcn_mfma_f32_16x16x32_bf16(aih[kk], wil[kk][nt], acc[nt], 0,0,0);
          acc[nt] = __builtin_amdgcn_mfma_f32_16x16x32_bf16(ail[kk], wih[kk][nt], acc[nt], 0,0,0);
        }
    }
    #pragma unroll
    for (int nt = 0; nt < 2; nt++)
      #pragma unroll
      for (int r = 0; r < 4; r++)
        red[quad*4 + r][nt*16 + col][wv] = acc[nt][r];
    __syncthreads();

    // epilogue: one (batch,j) per thread; publish packet FIRST (critical path)
    {
      floatx4 p = *(const floatx4*)red[eb][ej];
      float pre = p[0] + p[1] + p[2] + p[3] + brec_e;
      float e2x = __expf(2.0f*pre);
      float rec = 1.0f - 2.0f/(e2x + 1.0f);   // tanh, robust at +-inf
      int j = jb*NS + ej;
      float hprev = bf2f(hAhi[eb][j]) + bf2f(hAlo[eb][j]);
      float hnew = (1.0f - DTC)*hprev + DTC*rec;
      unsigned short h_ = f2bf(hnew);
      unsigned short l_ = f2bf(hnew - bf2f(h_));
      if (t < Tn-1){
        u64 pkt = (((u64)(unsigned)(t+1)) << 32) | ((unsigned)h_ << 16) | (unsigned)l_;
        __hip_atomic_store(&Hpkt[(((size_t)((t+1)&1)*NG + g)*MB + eb)*Hn + j], pkt,
                           __ATOMIC_RELAXED, __HIP_MEMORY_SCOPE_AGENT);
      }
      __builtin_nontemporal_store(h_, &hs[((size_t)bglob*Tn + t)*Hn + j]);
    }
    __syncthreads();  // protect hA/red reuse next iteration
  }
}

// out[bt,o] = sum_h hs[bt,h]*wo[h,o]; fp32 out, wo in hi+lo bf16
__global__ __launch_bounds__(256,1) void out_gemm(
    const unsigned short* __restrict__ hs,
    const float* __restrict__ wo,
    float* __restrict__ out)
{
  const int tid = threadIdx.x, bid = blockIdx.x;
  const int wv = tid >> 6, lane = tid & 63, col = lane & 15, quad = lane >> 4;
  const int m0 = bid*64;
  __shared__ __align__(16) unsigned short hsA[64][520];

  for (int c = tid; c < 64*64; c += 256){
    int r = c >> 6, cc = (c & 63)*8;
    *(short8*)&hsA[r][cc] = *(const short8*)(hs + (size_t)(m0 + r)*Hn + cc);
  }
  short8 boh[16], bol[16];
  #pragma unroll
  for (int kk = 0; kk < 16; kk++){
    float tmp[8];
    #pragma unroll
    for (int e = 0; e < 8; e++) tmp[e] = wo[(size_t)(kk*32 + quad*8 + e)*On + wv*16 + col];
    split8(tmp, boh[kk], bol[kk]);
  }
  __syncthreads();

  floatx4 acc[4] = {{0.f,0.f,0.f,0.f},{0.f,0.f,0.f,0.f},{0.f,0.f,0.f,0.f},{0.f,0.f,0.f,0.f}};
  #pragma unroll
  for (int kk = 0; kk < 16; kk++){
    int k = kk*32 + quad*8;
    #pragma unroll
    for (int ms = 0; ms < 4; ms++){
      short8 a = *(const short8*)&hsA[ms*16 + col][k];
      acc[ms] = __builtin_amdgcn_mfma_f32_16x16x32_bf16(a, boh[kk], acc[ms], 0,0,0);
      acc[ms] = __builtin_amdgcn_mfma_f32_16x16x32_bf16(a, bol[kk], acc[ms], 0,0,0);
    }
  }
  #pragma unroll
  for (int ms = 0; ms < 4; ms++)
    #pragma unroll
    for (int r = 0; r < 4; r++){
      int m = m0 + ms*16 + quad*4 + r;
      out[(size_t)m*On + wv*16 + col] = acc[ms][r];
    }
}

extern "C" void kernel_launch(void* const* d_in, const int* in_sizes, int n_in,
                              void* d_out, int out_size, void* d_ws, size_t ws_size,
                              hipStream_t stream){
  const float* inp  = (const float*)d_in[0];
  const float* wi   = (const float*)d_in[1];
  const float* wrec = (const float*)d_in[2];
  const float* wo   = (const float*)d_in[3];
  const float* brec = (const float*)d_in[4];
  const float* h0   = (const float*)d_in[5];
  float* out = (float*)d_out;

  char* ws = (char*)d_ws;
  unsigned short* hs = (unsigned short*)ws;                 // 64 MB
  u64* Hpkt = (u64*)(ws + (size_t)Bn*Tn*Hn*2);              // 512 KB
  // ws is re-poisoned to 0xAA before every launch: packet tags read 0xAAAAAAAA,
  // which never equals a wanted tag (0..1023) -- no zeroing pass needed.

  rnn_scan<<<NG*NJ, 256, 0, stream>>>(inp, wi, wrec, brec, h0, hs, Hpkt);
  out_gemm<<<(Bn*Tn)/64, 256, 0, stream>>>(hs, wo, out);
}

// Round 4
// 3492.487 us; speedup vs baseline: 1.2248x; 1.2248x over previous
//
#include <hip/hip_runtime.h>

#define Tn 1024
#define Bn 64
#define In_ 64
#define Hn 512
#define On 64
#define DTC 0.5f

typedef __attribute__((ext_vector_type(8))) short short8;   // bf16x8 MFMA frag
typedef __attribute__((ext_vector_type(4))) short short4v;  // bf16x4 (8B)
typedef __attribute__((ext_vector_type(4))) float floatx4;  // MFMA C frag
typedef unsigned long long u64;

__device__ __forceinline__ float bf2f(unsigned short u){
  union{unsigned int i; float f;} v; v.i = ((unsigned int)u)<<16; return v.f;
}
__device__ __forceinline__ unsigned short f2bf(float f){   // RNE
  union{float f; unsigned int i;} v; v.f=f;
  unsigned int x=v.i;
  return (unsigned short)((x + 0x7fffu + ((x>>16)&1u))>>16);
}
__device__ __forceinline__ short8 cvt8(const float* p){
  short8 v;
  #pragma unroll
  for (int e=0;e<8;e++) v[e] = (short)f2bf(p[e]);
  return v;
}
// raw LDS-only barrier: no vmcnt(0) drain (global stores keep flying)
__device__ __forceinline__ void barrier_lds(){
  asm volatile("s_waitcnt lgkmcnt(0)\n\ts_barrier" ::: "memory");
}

// ---------------- xproj: xp[t][b][j] = inp[b][t][:]@wi[:,j] + brec[j] (bf16) --------
__global__ __launch_bounds__(256,2) void xproj_kernel(
    const float* __restrict__ inp, const float* __restrict__ wi,
    const float* __restrict__ brec, unsigned short* __restrict__ xp)
{
  const int t = blockIdx.x, tid = threadIdx.x;
  const int wv = tid>>6, lane = tid&63, col = lane&15, quad = lane>>4;
  __shared__ __align__(16) unsigned short inA[64*80];   // [b][i], pad 80
  {
    int r = tid>>2, i0 = (tid&3)*16;
    const float* src = inp + ((size_t)r*Tn + t)*In_ + i0;
    unsigned short tmp[16];
    #pragma unroll
    for (int q=0;q<16;q++) tmp[q] = f2bf(src[q]);
    *(short8*)&inA[r*80 + i0]     = *(short8*)&tmp[0];
    *(short8*)&inA[r*80 + i0 + 8] = *(short8*)&tmp[8];
  }
  const int wnb = wv*128;
  short8 bw[8][2];
  float brecv[8];
  #pragma unroll
  for (int nt=0;nt<8;nt++){
    int j = wnb + nt*16 + col;
    brecv[nt] = brec[j];
    #pragma unroll
    for (int ks=0;ks<2;ks++){
      float tmp[8];
      #pragma unroll
      for (int e=0;e<8;e++) tmp[e] = wi[(size_t)(ks*32 + quad*8 + e)*Hn + j];
      bw[nt][ks] = cvt8(tmp);
    }
  }
  __syncthreads();
  floatx4 acc[4][8];
  #pragma unroll
  for (int mt=0;mt<4;mt++)
    #pragma unroll
    for (int nt=0;nt<8;nt++) acc[mt][nt] = (floatx4){0.f,0.f,0.f,0.f};
  #pragma unroll
  for (int ks=0;ks<2;ks++)
    #pragma unroll
    for (int mt=0;mt<4;mt++){
      short8 ar = *(const short8*)&inA[(mt*16+col)*80 + ks*32 + quad*8];
      #pragma unroll
      for (int nt=0;nt<8;nt++)
        acc[mt][nt] = __builtin_amdgcn_mfma_f32_16x16x32_bf16(ar, bw[nt][ks], acc[mt][nt],0,0,0);
    }
  #pragma unroll
  for (int mt=0;mt<4;mt++)
    #pragma unroll
    for (int nt=0;nt<8;nt++)
      #pragma unroll
      for (int r=0;r<4;r++){
        int b = mt*16 + quad*4 + r;
        int j = wnb + nt*16 + col;
        xp[((size_t)t*Bn + b)*Hn + j] = f2bf(acc[mt][nt][r] + brecv[nt]);
      }
}

// ------------- wrec_pack: bf16 A-frags for k in [320,384), streamed by scan ---------
__global__ __launch_bounds__(256,1) void wrec_pack(
    const float* __restrict__ wrec, unsigned short* __restrict__ wrecB)
{
  int gl = blockIdx.x*256 + threadIdx.x;      // 0..4095
  int fi = gl>>6, lane = gl&63;               // fi = gmt*2+ksx
  int gmt = fi>>1, ksx = fi&1;
  int j = gmt*16 + (lane&15);
  int k = 320 + ksx*32 + (lane>>4)*8;
  short8 v = cvt8(wrec + (size_t)j*Hn + k);
  *(short8*)(wrecB + (size_t)gl*8) = v;
}

// ------------- scan: 4 blocks x 512 threads; one CU per 16-batch group --------------
// Transposed compute: pre^T[j][b] = sum_k wrec[j][k] h[b][k].
// A=wrec: ks 0..9 VGPR, ks 10..11 streamed (wrecB, L1-hot), ks 12..15 LDS (128KB).
// B=h: bf16 frag-layout in LDS (16KB); fp32 master in registers (lane-owned).
// Sync = 2 LDS-only barriers/step. Zero cross-block traffic.
__global__ __launch_bounds__(512,2) void rnn_scan(
    const float* __restrict__ wrec, const float* __restrict__ h0,
    const unsigned short* xp,            // ws+64KB  [T][B][H] bf16 (aliases hs+1 slot)
    const unsigned short* __restrict__ wrecB,
    unsigned short* hs)                  // ws       [T][B][H] bf16
{
  const int tid  = threadIdx.x;
  const int g    = blockIdx.x;          // batch group: b in [16g, 16g+16)
  const int wv   = tid >> 6;            // 0..7, owns j in [64wv, 64wv+64)
  const int lane = tid & 63;
  const int col  = lane & 15;
  const int quad = lane >> 4;
  const int wbase = wv*64;

  __shared__ __align__(16) unsigned short wrecL[65536]; // 128KB: frag (gmt*4+ks2)*512+lane*8
  __shared__ __align__(16) unsigned short hA[8192];     // 16KB:  frag ks*512+lane*8

  // A-frags ks 0..9 (k<320), register-resident
  short8 awr[4][10];
  #pragma unroll
  for (int mt=0;mt<4;mt++)
    #pragma unroll
    for (int ks=0;ks<10;ks++){
      int j = wbase + mt*16 + col;
      int k = ks*32 + quad*8;
      awr[mt][ks] = cvt8(wrec + (size_t)j*Hn + k);
    }
  // A-frags ks 12..15 (k>=384) -> LDS
  #pragma unroll
  for (int mt=0;mt<4;mt++)
    #pragma unroll
    for (int ks2=0;ks2<4;ks2++){
      int j = wbase + mt*16 + col;
      int k = 384 + ks2*32 + quad*8;
      short8 v = cvt8(wrec + (size_t)j*Hn + k);
      *(short8*)&wrecL[(((wv*4+mt)*4 + ks2))*512 + lane*8] = v;
    }
  // h0 -> hA (bf16, frag layout: element (b,k) at ((k>>5)*64+((k>>3)&3)*16+b)*8+(k&7))
  for (int idx = tid; idx < 16*Hn; idx += 512){
    int b = idx >> 9, k = idx & 511;
    hA[(((k>>5)*64 + ((k>>3)&3)*16 + b))*8 + (k&7)] = f2bf(h0[k]);
  }
  // fp32 h master: lane owns (b=col, j = wbase+mt*16+quad*4+r)
  float hm[4][4];
  #pragma unroll
  for (int mt=0;mt<4;mt++)
    #pragma unroll
    for (int r=0;r<4;r++) hm[mt][r] = h0[wbase + mt*16 + quad*4 + r];

  floatx4 acc[4];
  #pragma unroll
  for (int mt=0;mt<4;mt++) acc[mt] = (floatx4){0.f,0.f,0.f,0.f};

  const size_t row = (size_t)(g*16 + col);   // global batch for this lane
  __syncthreads();

  for (int t = 0; t < Tn; t++){
    // prefetch: streamed A-frags (ksx=0) + xproj values for this step
    short8 wst[4];
    u64 xv[4];
    #pragma unroll
    for (int mt=0;mt<4;mt++)
      wst[mt] = *(const short8*)(wrecB + (size_t)(((wv*4+mt)*2 + 0)*64 + lane)*8);
    #pragma unroll
    for (int mt=0;mt<4;mt++)
      xv[mt] = *(const u64*)(xp + (size_t)t*(Bn*Hn) + row*Hn + wbase + mt*16 + quad*4);

    // K-sweep: B-frag (h) from hA, A-frag per source
    #pragma unroll
    for (int ks=0;ks<10;ks++){
      short8 hb = *(const short8*)&hA[ks*512 + lane*8];
      #pragma unroll
      for (int mt=0;mt<4;mt++)
        acc[mt] = __builtin_amdgcn_mfma_f32_16x16x32_bf16(awr[mt][ks], hb, acc[mt],0,0,0);
    }
    {  // ks 10 (streamed pass 0)
      short8 hb = *(const short8*)&hA[10*512 + lane*8];
      #pragma unroll
      for (int mt=0;mt<4;mt++)
        acc[mt] = __builtin_amdgcn_mfma_f32_16x16x32_bf16(wst[mt], hb, acc[mt],0,0,0);
    }
    #pragma unroll
    for (int mt=0;mt<4;mt++)   // reload streamed frags (ksx=1); hidden under ks12..15
      wst[mt] = *(const short8*)(wrecB + (size_t)(((wv*4+mt)*2 + 1)*64 + lane)*8);
    #pragma unroll
    for (int ks2=0;ks2<4;ks2++){  // ks 12..15 (LDS A)
      short8 hb = *(const short8*)&hA[(12+ks2)*512 + lane*8];
      #pragma unroll
      for (int mt=0;mt<4;mt++){
        short8 aw = *(const short8*)&wrecL[(((wv*4+mt)*4 + ks2))*512 + lane*8];
        acc[mt] = __builtin_amdgcn_mfma_f32_16x16x32_bf16(aw, hb, acc[mt],0,0,0);
      }
    }
    {  // ks 11 (streamed pass 1)
      short8 hb = *(const short8*)&hA[11*512 + lane*8];
      #pragma unroll
      for (int mt=0;mt<4;mt++)
        acc[mt] = __builtin_amdgcn_mfma_f32_16x16x32_bf16(wst[mt], hb, acc[mt],0,0,0);
    }

    barrier_lds();   // all hA/wrecL reads done CU-wide before epilogue writes hA

    // epilogue: lane owns (b=col, 16 j's); C layout row=j(quad*4+r), col=b
    #pragma unroll
    for (int mt=0;mt<4;mt++){
      u64 x = xv[mt];
      unsigned short hv[4];
      #pragma unroll
      for (int r=0;r<4;r++){
        float pre = acc[mt][r] + bf2f((unsigned short)(x >> (16*r)));
        float e2x = __expf(2.0f*pre);
        float rec = 1.0f - 2.0f/(e2x + 1.0f);       // tanh, robust at +-inf
        float hn  = (1.0f-DTC)*hm[mt][r] + DTC*rec;
        hm[mt][r] = hn;
        hv[r] = f2bf(hn);
      }
      int j4 = wbase + mt*16 + quad*4;
      // hA write (b=col, j4..j4+3) in frag layout -> ds_write_b64
      *(short4v*)&hA[(((j4>>5)*64 + ((j4>>3)&3)*16 + col))*8 + (j4&7)] = *(short4v*)hv;
      // hs[t][b][j4..j4+3]
      u64 pk = (u64)hv[0] | ((u64)hv[1]<<16) | ((u64)hv[2]<<32) | ((u64)hv[3]<<48);
      __builtin_nontemporal_store(pk, (u64*)(hs + (size_t)t*(Bn*Hn) + row*Hn + j4));
      acc[mt] = (floatx4){0.f,0.f,0.f,0.f};
    }
    barrier_lds();   // hA(t+1) visible before next step's reads
  }
}

// ------------- out: out[b][t][o] = hs[t][b][:] @ wo ; rows m = t*64+b ---------------
__global__ __launch_bounds__(256,1) void out_gemm(
    const unsigned short* __restrict__ hs,
    const float* __restrict__ wo,
    float* __restrict__ out)
{
  const int tid = threadIdx.x, bid = blockIdx.x;
  const int wv = tid >> 6, lane = tid & 63, col = lane & 15, quad = lane >> 4;
  const int m0 = bid*64;
  __shared__ __align__(16) unsigned short hsA[64][520];

  for (int c = tid; c < 64*64; c += 256){
    int r = c >> 6, cc = (c & 63)*8;
    *(short8*)&hsA[r][cc] = *(const short8*)(hs + (size_t)(m0 + r)*Hn + cc);
  }
  short8 boh[16], bol[16];
  #pragma unroll
  for (int kk = 0; kk < 16; kk++){
    float tmp[8];
    #pragma unroll
    for (int e = 0; e < 8; e++) tmp[e] = wo[(size_t)(kk*32 + quad*8 + e)*On + wv*16 + col];
    #pragma unroll
    for (int e = 0; e < 8; e++){
      unsigned short h = f2bf(tmp[e]);
      boh[kk][e] = (short)h;
      bol[kk][e] = (short)f2bf(tmp[e] - bf2f(h));
    }
  }
  __syncthreads();

  floatx4 acc[4];
  #pragma unroll
  for (int ms=0;ms<4;ms++) acc[ms] = (floatx4){0.f,0.f,0.f,0.f};
  #pragma unroll
  for (int kk = 0; kk < 16; kk++){
    int k = kk*32 + quad*8;
    #pragma unroll
    for (int ms = 0; ms < 4; ms++){
      short8 a = *(const short8*)&hsA[ms*16 + col][k];
      acc[ms] = __builtin_amdgcn_mfma_f32_16x16x32_bf16(a, boh[kk], acc[ms], 0,0,0);
      acc[ms] = __builtin_amdgcn_mfma_f32_16x16x32_bf16(a, bol[kk], acc[ms], 0,0,0);
    }
  }
  #pragma unroll
  for (int ms = 0; ms < 4; ms++)
    #pragma unroll
    for (int r = 0; r < 4; r++){
      int m = m0 + ms*16 + quad*4 + r;     // m = t*64 + b
      int b = m & 63, tt = m >> 6;
      out[((size_t)b*Tn + tt)*On + wv*16 + col] = acc[ms][r];
    }
}

extern "C" void kernel_launch(void* const* d_in, const int* in_sizes, int n_in,
                              void* d_out, int out_size, void* d_ws, size_t ws_size,
                              hipStream_t stream){
  const float* inp  = (const float*)d_in[0];
  const float* wi   = (const float*)d_in[1];
  const float* wrec = (const float*)d_in[2];
  const float* wo   = (const float*)d_in[3];
  const float* brec = (const float*)d_in[4];
  const float* h0   = (const float*)d_in[5];
  float* out = (float*)d_out;

  char* ws = (char*)d_ws;
  // hs slots: ws + t*64KB. xp slots: ws + 64KB + t*64KB (= hs slot t+1).
  // Scan step t writes hs[t] (destroys xp[t-1], already consumed; per-group
  // b-slices disjoint, so cross-block skew is safe). Total 64MB+64KB.
  unsigned short* hs = (unsigned short*)ws;
  unsigned short* xp = (unsigned short*)(ws + 65536);
  unsigned short* wrecB = (unsigned short*)(ws + (size_t)Tn*Bn*Hn*2 + 65536); // 64KB

  xproj_kernel<<<Tn, 256, 0, stream>>>(inp, wi, brec, xp);
  wrec_pack  <<<16, 256, 0, stream>>>(wrec, wrecB);
  rnn_scan   <<<4, 512, 0, stream>>>(wrec, h0, xp, wrecB, hs);
  out_gemm   <<<(Bn*Tn)/64, 256, 0, stream>>>(hs, wo, out);
}